// Round 22
// baseline (111.673 us; speedup 1.0000x reference)
//
#include <hip/hip_runtime.h>
#include <hip/hip_bf16.h>
#include <hip/hip_fp16.h>

typedef __bf16 bf16x8 __attribute__((ext_vector_type(8)));
typedef _Float16 h8_t __attribute__((ext_vector_type(8)));
typedef _Float16 v2h __attribute__((ext_vector_type(2)));
typedef short short8 __attribute__((ext_vector_type(8)));
typedef float f32x4 __attribute__((ext_vector_type(4)));

union BF8 { short8 s; bf16x8 b; };
union H8  { short8 s; h8_t h; unsigned w[4]; };
union HU  { _Float16 f; unsigned short u; };

#define N_NODES 4096
#define F_IN 512
#define F_OUT 64
#define NHEAD 8
#define HID 512
#define NCLS 10
#define GAT_ALPHA 0.2f
#define MSPLIT 4
#define WST 4096
#define NWORD (N_NODES / 64)
#define RB 32             // att1 rows per block
#define CB 128            // att1 staged cols per tile
#define QN (N_NODES / MSPLIT)           // 1024 cols per quarter
#define NIT (QN / CB)                   // 8
#define RB2 16            // att2 rows per block
#define MS2 8             // att2 m-splits (waves per block)
#define MT2 (N_NODES / MS2 / 64)        // 8 tiles per wave

#define PACK_BLOCKS (N_NODES * NWORD / 4)          // 65536
#define XCVT_BLOCKS (N_NODES * F_IN / 8 / 256)     // 1024
#define WCVT_BLOCKS (NHEAD * F_OUT * F_IN / 8 / 256) // 128

#if defined(__has_builtin)
#if __has_builtin(__builtin_amdgcn_fdot2)
#define FDOT2(a, b, c) __builtin_amdgcn_fdot2((a), (b), (c), false)
#endif
#endif
#ifndef FDOT2
#define FDOT2(a, b, c) ((c) + (float)(a)[0] * (float)(b)[0] + (float)(a)[1] * (float)(b)[1])
#endif

__device__ inline unsigned short f2bf(float f) {
  unsigned u = __builtin_bit_cast(unsigned, f);
  unsigned r = (u + 0x7FFFu + ((u >> 16) & 1u)) >> 16;
  return (unsigned short)r;
}
__device__ inline float bf2f(unsigned short h) {
  unsigned u = ((unsigned)h) << 16;
  return __builtin_bit_cast(float, u);
}

// ------- pack adjacency bits + x->bf16 + W->Wt[h][o][k] bf16 (one kernel) --
__global__ __launch_bounds__(256) void pack_prep_kernel(
    const int* __restrict__ adj, unsigned long long* __restrict__ bits,
    const float* __restrict__ x, unsigned short* __restrict__ xbf,
    const float* __restrict__ W, unsigned short* __restrict__ Wt) {
  const int b = blockIdx.x;
  const int tid = threadIdx.x;
  if (b < PACK_BLOCKS) {
    int wid = b * 4 + (tid >> 6);
    int l = tid & 63;
    unsigned long long m = __ballot(adj[(size_t)wid * 64 + l] != 0);
    if (l == 0) bits[wid] = m;
  } else if (b < PACK_BLOCKS + XCVT_BLOCKS) {
    int idx = (b - PACK_BLOCKS) * 256 + tid;
    const float* src = x + (size_t)idx * 8;
    float4 v0 = *(const float4*)src;
    float4 v1 = *(const float4*)(src + 4);
    short8 sv;
    sv[0]=f2bf(v0.x); sv[1]=f2bf(v0.y); sv[2]=f2bf(v0.z); sv[3]=f2bf(v0.w);
    sv[4]=f2bf(v1.x); sv[5]=f2bf(v1.y); sv[6]=f2bf(v1.z); sv[7]=f2bf(v1.w);
    *(short8*)&xbf[(size_t)idx * 8] = sv;
  } else {
    int t2 = (b - PACK_BLOCKS - XCVT_BLOCKS) * 256 + tid;   // [0, 32768)
    int h   = t2 >> 12;
    int rem = t2 & 4095;
    int o   = rem >> 6;
    int k8  = rem & 63;
    const float* src = W + ((size_t)(h * F_IN) + k8 * 8) * F_OUT + o;
    short8 sv;
    #pragma unroll
    for (int j = 0; j < 8; ++j) sv[j] = (short)f2bf(src[(size_t)j * F_OUT]);
    *(short8*)&Wt[((size_t)(h * F_OUT) + o) * F_IN + k8 * 8] = sv;
  }
}

// ---------------- GEMM1: wave-private DMA staging, barrier-free k-loop -----
// wave w computes out rows w*16..+16; stages its OWN full B k-slice (4 ops,
// replicated across waves) + A slice (1 op). Zero __syncthreads in the loop.
__global__ __launch_bounds__(256) void gemm1_kernel(
    const unsigned short* __restrict__ xbf, const unsigned short* __restrict__ Wt,
    const float* __restrict__ a1, const float* __restrict__ a2,
    unsigned short* __restrict__ WhbT, float* __restrict__ rho1,
    unsigned short* __restrict__ E2f16, unsigned short* __restrict__ E2sf16) {
  __shared__ __align__(16) short As[4][512];     // [wave][l*8] A slice
  __shared__ __align__(16) short Bw[4][4 * 512]; // [wave][fc*512 + l*8] full B
  __shared__ short Ts[64 * 72];                  // transposed f16 out tile
  const int bx = blockIdx.x;
  const int h  = blockIdx.y;
  const int t  = threadIdx.x;
  const int w  = t >> 6, l = t & 63;
  const int lr = l & 15, ls = l >> 4;
  const unsigned short* asrc = xbf + (size_t)(bx * 64 + w * 16 + lr) * F_IN + ls * 8;
  const unsigned short* bsrc0 = Wt + (size_t)(h * F_OUT + lr) * F_IN + ls * 8;

#define G1DMA(k0) do {                                                        \
    __builtin_amdgcn_global_load_lds(                                         \
        (const __attribute__((address_space(1))) void*)(asrc + (k0)),         \
        (__attribute__((address_space(3))) void*)&As[w][0], 16, 0, 0);        \
    _Pragma("unroll")                                                         \
    for (int fc = 0; fc < 4; ++fc)                                            \
      __builtin_amdgcn_global_load_lds(                                       \
          (const __attribute__((address_space(1))) void*)(bsrc0 + (size_t)(fc * 16) * F_IN + (k0)), \
          (__attribute__((address_space(3))) void*)&Bw[w][fc * 512], 16, 0, 0); \
  } while (0)

  f32x4 acc[4] = {};
  G1DMA(0);
  for (int it = 0; it < F_IN / 32; ++it) {
    asm volatile("s_waitcnt vmcnt(0)" ::: "memory");
    BF8 a, b0, b1, b2, b3;
    a.s  = *(short8*)&As[w][l * 8];
    b0.s = *(short8*)&Bw[w][0 * 512 + l * 8];
    b1.s = *(short8*)&Bw[w][1 * 512 + l * 8];
    b2.s = *(short8*)&Bw[w][2 * 512 + l * 8];
    b3.s = *(short8*)&Bw[w][3 * 512 + l * 8];
    asm volatile("s_waitcnt lgkmcnt(0)" ::: "memory");
    __builtin_amdgcn_sched_barrier(0);
    if (it + 1 < F_IN / 32) G1DMA((it + 1) * 32);
    __builtin_amdgcn_sched_barrier(0);
    acc[0] = __builtin_amdgcn_mfma_f32_16x16x32_bf16(a.b, b0.b, acc[0], 0, 0, 0);
    acc[1] = __builtin_amdgcn_mfma_f32_16x16x32_bf16(a.b, b1.b, acc[1], 0, 0, 0);
    acc[2] = __builtin_amdgcn_mfma_f32_16x16x32_bf16(a.b, b2.b, acc[2], 0, 0, 0);
    acc[3] = __builtin_amdgcn_mfma_f32_16x16x32_bf16(a.b, b3.b, acc[3], 0, 0, 0);
  }
#undef G1DMA
  #pragma unroll
  for (int fc = 0; fc < 4; ++fc)
    #pragma unroll
    for (int j = 0; j < 4; ++j) {
      HU hu; hu.f = (_Float16)acc[fc][j];
      Ts[(fc * 16 + lr) * 72 + (w * 16 + ls * 4 + j)] = (short)hu.u;   // C/D: row=(l>>4)*4+j, col=l&15
    }
  __syncthreads();
  {
    int col = t >> 2, seg = t & 3;
    short8 o0 = *(short8*)&Ts[col * 72 + seg * 16];
    short8 o1 = *(short8*)&Ts[col * 72 + seg * 16 + 8];
    unsigned short* dst = WhbT + (size_t)(h * F_OUT + col) * WST + bx * 64 + seg * 16;
    *(short8*)dst = o0;
    *(short8*)(dst + 8) = o1;
  }
  float a1c[4], a2c[4];
  #pragma unroll
  for (int fc = 0; fc < 4; ++fc) {
    a1c[fc] = a1[h * F_OUT + fc * 16 + lr];
    a2c[fc] = a2[h * F_OUT + fc * 16 + lr];
  }
  #pragma unroll
  for (int j = 0; j < 4; ++j) {
    float s1 = 0.f, s2 = 0.f;
    #pragma unroll
    for (int fc = 0; fc < 4; ++fc) { s1 += acc[fc][j] * a1c[fc]; s2 += acc[fc][j] * a2c[fc]; }
    #pragma unroll
    for (int off = 1; off <= 8; off <<= 1) {
      s1 += __shfl_xor(s1, off, 64);
      s2 += __shfl_xor(s2, off, 64);
    }
    if (lr == 0) {
      int row = bx * 64 + w * 16 + ls * 4 + j;
      int idx = h * N_NODES + row;
      rho1[idx] = __expf((GAT_ALPHA - 1.f) * s1);
      HU u1; u1.f = (_Float16)__expf(s2);
      HU u2; u2.f = (_Float16)__expf(GAT_ALPHA * s2);
      E2f16[idx]  = u1.u;
      E2sf16[idx] = u2.u;
    }
  }
}

// ---------------- ATT1: LDS tables + CB=128 tiles (FROZEN, 44.4 us) --------
__global__ __launch_bounds__(256, 2) void att1_kernel(
    const unsigned long long* __restrict__ adjbits,
    const float* __restrict__ rho1,
    const unsigned short* __restrict__ E2f16, const unsigned short* __restrict__ E2sf16,
    const unsigned short* __restrict__ WhbT,
    unsigned short* __restrict__ accPh, float* __restrict__ SP) {
  __shared__ __align__(16) short Bt[4][64 * CB];            // 64 KB
  __shared__ __align__(16) unsigned short Et[4][2][QN];     // 16 KB tables
  const int nb = blockIdx.x * RB;
  const int q  = blockIdx.y;
  const int t  = threadIdx.x;
  const int wl = t >> 6;                    // wave in block
  const int h  = blockIdx.z * 4 + wl;       // global head
  const int l  = t & 63;
  const int r  = l & 15, s = l >> 4;

  const float rho0  = rho1[h * N_NODES + nb + r];
  const float rho1v = rho1[h * N_NODES + nb + 16 + r];
  const v2h rh0 = {(_Float16)rho0, (_Float16)rho0};
  const v2h rh1 = {(_Float16)rho1v, (_Float16)rho1v};
  const v2h ones = {(_Float16)1.0f, (_Float16)1.0f};
  const unsigned short* __restrict__ E2h  = E2f16  + h * N_NODES;
  const unsigned short* __restrict__ E2sh = E2sf16 + h * N_NODES;
  const unsigned long long* __restrict__ ab0 = adjbits + (size_t)(nb + r) * NWORD;
  const unsigned long long* __restrict__ ab1 = adjbits + (size_t)(nb + 16 + r) * NWORD;

  const int tb0 = q * QN;

#define DMAQ1(tbD) do {                                                       \
    _Pragma("unroll")                                                         \
    for (int i = 0; i < 16; ++i) {                                            \
      const int row = 4 * i + (l >> 4);                                       \
      const int gsw = ((l & 15) ^ (row & 15)) * 8;                            \
      __builtin_amdgcn_global_load_lds(                                       \
        (const __attribute__((address_space(1))) void*)                       \
            (WhbT + (size_t)(h * F_OUT + row) * WST + (tbD) + gsw),           \
        (__attribute__((address_space(3))) void*)&Bt[wl][i * 512], 16, 0, 0); \
    }                                                                         \
  } while (0)

  DMAQ1(tb0);
  #pragma unroll
  for (int i = 0; i < 2; ++i) {
    __builtin_amdgcn_global_load_lds(
        (const __attribute__((address_space(1))) void*)(E2h + tb0 + i * 512 + l * 8),
        (__attribute__((address_space(3))) void*)&Et[wl][0][i * 512], 16, 0, 0);
    __builtin_amdgcn_global_load_lds(
        (const __attribute__((address_space(1))) void*)(E2sh + tb0 + i * 512 + l * 8),
        (__attribute__((address_space(3))) void*)&Et[wl][1][i * 512], 16, 0, 0);
  }
  unsigned long long mk0a = ab0[tb0 >> 6],       mk1a = ab1[tb0 >> 6];
  unsigned long long mk0b = ab0[(tb0 >> 6) + 1], mk1b = ab1[(tb0 >> 6) + 1];
  asm volatile("s_waitcnt vmcnt(0)" ::: "memory");

  float S0 = 0.f, S1 = 0.f;
  f32x4 acc[2][4] = {};
  for (int it = 0; it < NIT; ++it) {
    const int base = it * CB;
    H8 a0[4], a1f[4];
    #pragma unroll
    for (int kf = 0; kf < 4; ++kf) {
      uint4 ew = *(const uint4*)&Et[wl][0][base + kf * 32 + s * 8];
      uint4 sw = *(const uint4*)&Et[wl][1][base + kf * 32 + s * 8];
      const unsigned ewa[4] = {ew.x, ew.y, ew.z, ew.w};
      const unsigned swa[4] = {sw.x, sw.y, sw.z, sw.w};
      const unsigned sh = (kf & 1) * 32 + s * 8;
      const unsigned bm0 = (unsigned)((kf < 2 ? mk0a : mk0b) >> sh) & 0xffu;
      const unsigned bm1 = (unsigned)((kf < 2 ? mk1a : mk1b) >> sh) & 0xffu;
      #pragma unroll
      for (int p = 0; p < 4; ++p) {
        const v2h e2 = __builtin_bit_cast(v2h, ewa[p]);
        const v2h es = __builtin_bit_cast(v2h, swa[p]);
        const unsigned lo0 = ((bm0 >> (2 * p)) & 1u) ? 0x0000FFFFu : 0u;
        const unsigned hi0 = ((bm0 >> (2 * p + 1)) & 1u) ? 0xFFFF0000u : 0u;
        unsigned q0w = __builtin_bit_cast(unsigned, __builtin_elementwise_max(e2, (v2h)(rh0 * es))) & (lo0 | hi0);
        S0 = FDOT2(__builtin_bit_cast(v2h, q0w), ones, S0);
        a0[kf].w[p] = q0w;
        const unsigned lo1 = ((bm1 >> (2 * p)) & 1u) ? 0x0000FFFFu : 0u;
        const unsigned hi1 = ((bm1 >> (2 * p + 1)) & 1u) ? 0xFFFF0000u : 0u;
        unsigned q1w = __builtin_bit_cast(unsigned, __builtin_elementwise_max(e2, (v2h)(rh1 * es))) & (lo1 | hi1);
        S1 = FDOT2(__builtin_bit_cast(v2h, q1w), ones, S1);
        a1f[kf].w[p] = q1w;
      }
    }
    asm volatile("s_waitcnt vmcnt(0)" ::: "memory");   // B-DMA(it) done
    if (it + 1 < NIT) {
      const int wi = (tb0 + base + CB) >> 6;
      mk0a = ab0[wi]; mk1a = ab1[wi];
      mk0b = ab0[wi + 1]; mk1b = ab1[wi + 1];
    }
    H8 b[4][4];
    #pragma unroll
    for (int kf = 0; kf < 4; ++kf)
      #pragma unroll
      for (int fc = 0; fc < 4; ++fc)
        b[kf][fc].s = *(short8*)&Bt[wl][(fc * 16 + r) * CB + (((kf * 4 + s) ^ (r & 15)) * 8)];
    asm volatile("s_waitcnt lgkmcnt(0)" ::: "memory");
    __builtin_amdgcn_sched_barrier(0);
    if (it + 1 < NIT) DMAQ1(tb0 + base + CB);
    __builtin_amdgcn_sched_barrier(0);
    #pragma unroll
    for (int kf = 0; kf < 4; ++kf)
      #pragma unroll
      for (int fc = 0; fc < 4; ++fc) {
        acc[0][fc] = __builtin_amdgcn_mfma_f32_16x16x32_f16(a0[kf].h,  b[kf][fc].h, acc[0][fc], 0, 0, 0);
        acc[1][fc] = __builtin_amdgcn_mfma_f32_16x16x32_f16(a1f[kf].h, b[kf][fc].h, acc[1][fc], 0, 0, 0);
      }
  }
#undef DMAQ1

  S0 += __shfl_xor(S0, 16, 64); S0 += __shfl_xor(S0, 32, 64);
  S1 += __shfl_xor(S1, 16, 64); S1 += __shfl_xor(S1, 32, 64);
  if (s == 0) {
    SP[((size_t)q * NHEAD + h) * N_NODES + nb + r]      = S0;
    SP[((size_t)q * NHEAD + h) * N_NODES + nb + 16 + r] = S1;
  }
  #pragma unroll
  for (int rg = 0; rg < 2; ++rg)
    #pragma unroll
    for (int fc = 0; fc < 4; ++fc)
      #pragma unroll
      for (int j = 0; j < 4; ++j) {
        int n = nb + rg * 16 + s * 4 + j;          // C/D: row=(l>>4)*4+j
        int col = h * F_OUT + fc * 16 + r;         // C/D: col=l&15
        HU hu; hu.f = (_Float16)acc[rg][fc][j];
        accPh[((size_t)q * N_NODES + n) * HID + col] = hu.u;
      }
}

// ---------------- GEMM2 (fused reduce + ELU): accPh f16 -> Wh2T + tables ---
__global__ __launch_bounds__(256) void gemm2_kernel(
    const unsigned short* __restrict__ accPh, const float* __restrict__ SP,
    const float* __restrict__ Wo,
    const float* __restrict__ ao1, const float* __restrict__ ao2,
    unsigned short* __restrict__ Wh2T, float* __restrict__ rho_o,
    float* __restrict__ Eg2, float* __restrict__ Eg2s) {
  int n = blockIdx.x * 4 + (threadIdx.x >> 6);
  int l = threadIdx.x & 63;
  const int h = l >> 3;                    // head of this lane's 8 hid cols
  float Ssum = 0.f;
  #pragma unroll
  for (int q = 0; q < MSPLIT; ++q) Ssum += SP[((size_t)q * NHEAD + h) * N_NODES + n];
  float v[8] = {};
  #pragma unroll
  for (int q = 0; q < MSPLIT; ++q) {
    H8 u; u.s = *(const short8*)&accPh[((size_t)q * N_NODES + n) * HID + l * 8];
    #pragma unroll
    for (int j = 0; j < 8; ++j) v[j] += (float)u.h[j];
  }
  float rs = 1.0f / Ssum;
  float acc[NCLS] = {};
  #pragma unroll
  for (int j = 0; j < 8; ++j) {
    float e = v[j] * rs;
    e = e > 0.f ? e : (__expf(e) - 1.0f);
    float hv = bf2f(f2bf(e));              // keep bf16 hcat rounding
    const float* wrow = Wo + (l * 8 + j) * NCLS;
    #pragma unroll
    for (int c = 0; c < NCLS; ++c) acc[c] += hv * wrow[c];
  }
  #pragma unroll
  for (int c = 0; c < NCLS; ++c)
    #pragma unroll
    for (int off = 32; off > 0; off >>= 1) acc[c] += __shfl_xor(acc[c], off, 64);
  if (l == 0) {
    float s1 = 0.f, s2 = 0.f;
    #pragma unroll
    for (int c = 0; c < NCLS; ++c) {
      s1 += acc[c] * ao1[c];
      s2 += acc[c] * ao2[c];
    }
    #pragma unroll
    for (int c = 0; c < 16; ++c)
      Wh2T[(size_t)c * N_NODES + n] = (c < NCLS) ? f2bf(acc[c]) : (unsigned short)0;
    rho_o[n] = __expf((GAT_ALPHA - 1.f) * s1);
    Eg2[n]   = __expf(s2);
    Eg2s[n]  = __expf(GAT_ALPHA * s2);
  }
}

// ---------------- ATT2: MFMA PV (P @ Wh2T), in-block combine + log_softmax -
__global__ __launch_bounds__(512) void att2_kernel(
    const unsigned long long* __restrict__ adjbits,
    const float* __restrict__ rho_o,
    const float* __restrict__ Eg2, const float* __restrict__ Eg2s,
    const unsigned short* __restrict__ Wh2T, float* __restrict__ out) {
  __shared__ float Lacc[MS2][RB2][16];
  __shared__ float LS[MS2][RB2];
  const int nb = blockIdx.x * RB2;
  const int t  = threadIdx.x;
  const int w  = t >> 6;               // wave = m-split
  const int l  = t & 63;
  const int r  = l & 15, s = l >> 4;
  const int row = nb + r;
  const float ro = rho_o[row];
  const unsigned long long* __restrict__ ab = adjbits + (size_t)row * NWORD;
  const int tb0 = w * (N_NODES / MS2);

  float S = 0.f;
  f32x4 acc = {};
  for (int it = 0; it < MT2; ++it) {
    const int tb = tb0 + it * 64;
    const unsigned long long mk = ab[tb >> 6];
    BF8 a0[2], b0[2];
    #pragma unroll
    for (int kf = 0; kf < 2; ++kf) {
      const int cb = tb + kf * 32 + s * 8;
      b0[kf].s = *(const short8*)(Wh2T + (size_t)r * N_NODES + cb);
      float4 ea = *(const float4*)(Eg2 + cb);
      float4 eb = *(const float4*)(Eg2 + cb + 4);
      float4 sa = *(const float4*)(Eg2s + cb);
      float4 sb = *(const float4*)(Eg2s + cb + 4);
      float ev[8] = {ea.x, ea.y, ea.z, ea.w, eb.x, eb.y, eb.z, eb.w};
      float sv[8] = {sa.x, sa.y, sa.z, sa.w, sb.x, sb.y, sb.z, sb.w};
      const unsigned bm = (unsigned)(mk >> (kf * 32 + s * 8)) & 0xffu;
      #pragma unroll
      for (int j = 0; j < 8; ++j) {
        float qv = fmaxf(ev[j], ro * sv[j]);
        qv = ((bm >> j) & 1u) ? qv : 0.f;
        S += qv;
        a0[kf].b[j] = (__bf16)qv;
      }
    }
    #pragma unroll
    for (int kf = 0; kf < 2; ++kf)
      acc = __builtin_amdgcn_mfma_f32_16x16x32_bf16(a0[kf].b, b0[kf].b, acc, 0, 0, 0);
  }
  S += __shfl_xor(S, 16, 64);
  S += __shfl_xor(S, 32, 64);
  if (s == 0) LS[w][r] = S;
  #pragma unroll
  for (int j = 0; j < 4; ++j) Lacc[w][s * 4 + j][r] = acc[j];   // D row=s*4+j, col=r
  __syncthreads();
  if (t < 256) {
    const int rr = t >> 4, cc = t & 15;
    float Ssum = 0.f, vsum = 0.f;
    #pragma unroll
    for (int q = 0; q < MS2; ++q) { Ssum += LS[q][rr]; vsum += Lacc[q][rr][cc]; }
    float lo = vsum / Ssum;
    float lom = (cc < NCLS) ? lo : -1e30f;
    float mx = lom;
    #pragma unroll
    for (int off = 1; off <= 8; off <<= 1) mx = fmaxf(mx, __shfl_xor(mx, off, 64));
    float ex = (cc < NCLS) ? __expf(lo - mx) : 0.f;
    float se = ex;
    #pragma unroll
    for (int off = 1; off <= 8; off <<= 1) se += __shfl_xor(se, off, 64);
    float lse = mx + __logf(se);
    if (cc < NCLS) out[(size_t)(nb + rr) * NCLS + cc] = lo - lse;
  }
}

extern "C" void kernel_launch(void* const* d_in, const int* in_sizes, int n_in,
                              void* d_out, int out_size, void* d_ws, size_t ws_size,
                              hipStream_t stream) {
  (void)in_sizes; (void)n_in; (void)out_size; (void)ws_size;
  const float* x   = (const float*)d_in[0];
  const int*   adj = (const int*)d_in[1];
  const float* W   = (const float*)d_in[2];
  const float* a1  = (const float*)d_in[3];
  const float* a2  = (const float*)d_in[4];
  const float* Wo  = (const float*)d_in[5];
  const float* ao1 = (const float*)d_in[6];
  const float* ao2 = (const float*)d_in[7];
  float* out = (float*)d_out;

  char* ws = (char*)d_ws;
  unsigned long long* adjbits = (unsigned long long*)ws; ws += (size_t)N_NODES * NWORD * 8;
  unsigned short* WhbT= (unsigned short*)ws; ws += (size_t)HID * WST * 2;
  unsigned short* accPh = (unsigned short*)ws; ws += (size_t)MSPLIT * N_NODES * HID * 2;
  float* SP           = (float*)ws;          ws += (size_t)MSPLIT * NHEAD * N_NODES * 4;
  float* rho1         = (float*)ws;          ws += (size_t)NHEAD * N_NODES * 4;
  unsigned short* E2f16  = (unsigned short*)ws; ws += (size_t)NHEAD * N_NODES * 2;
  unsigned short* E2sf16 = (unsigned short*)ws; ws += (size_t)NHEAD * N_NODES * 2;
  unsigned short* Wh2T= (unsigned short*)ws; ws += (size_t)16 * N_NODES * 2;
  float* rho_o        = (float*)ws;          ws += (size_t)N_NODES * 4;
  float* Eg2          = (float*)ws;          ws += (size_t)N_NODES * 4;
  float* Eg2s         = (float*)ws;          ws += (size_t)N_NODES * 4;
  unsigned short* xbf = (unsigned short*)ws; ws += (size_t)N_NODES * F_IN * 2;
  unsigned short* Wt  = (unsigned short*)ws; ws += (size_t)NHEAD * F_OUT * F_IN * 2;

  pack_prep_kernel<<<PACK_BLOCKS + XCVT_BLOCKS + WCVT_BLOCKS, 256, 0, stream>>>(
      adj, adjbits, x, xbf, W, Wt);
  gemm1_kernel<<<dim3(64, 8), 256, 0, stream>>>(xbf, Wt, a1, a2, WhbT, rho1, E2f16, E2sf16);
  att1_kernel<<<dim3(N_NODES / RB, MSPLIT, 2), 256, 0, stream>>>(adjbits, rho1, E2f16, E2sf16, WhbT, accPh, SP);
  gemm2_kernel<<<N_NODES / 4, 256, 0, stream>>>(accPh, SP, Wo, ao1, ao2, Wh2T, rho_o, Eg2, Eg2s);
  att2_kernel<<<N_NODES / RB2, 512, 0, stream>>>(adjbits, rho_o, Eg2, Eg2s, Wh2T, out);
}

// Round 23
// 102.941 us; speedup vs baseline: 1.0848x; 1.0848x over previous
//
#include <hip/hip_runtime.h>
#include <hip/hip_bf16.h>
#include <hip/hip_fp16.h>

typedef __bf16 bf16x8 __attribute__((ext_vector_type(8)));
typedef _Float16 h8_t __attribute__((ext_vector_type(8)));
typedef _Float16 v2h __attribute__((ext_vector_type(2)));
typedef short short8 __attribute__((ext_vector_type(8)));
typedef float f32x4 __attribute__((ext_vector_type(4)));

union BF8 { short8 s; bf16x8 b; };
union H8  { short8 s; h8_t h; unsigned w[4]; };
union HU  { _Float16 f; unsigned short u; };

#define N_NODES 4096
#define F_IN 512
#define F_OUT 64
#define NHEAD 8
#define HID 512
#define NCLS 10
#define GAT_ALPHA 0.2f
#define MSPLIT 4
#define WST 4096
#define NWORD (N_NODES / 64)
#define RB 32             // att1 rows per block
#define CB 128            // att1 staged cols per tile
#define QN (N_NODES / MSPLIT)           // 1024 cols per quarter
#define NIT (QN / CB)                   // 8
#define RB2 16            // att2 rows per block
#define MS2 8             // att2 m-splits (waves per block)
#define MT2 (N_NODES / MS2 / 64)        // 8 tiles per wave

#define PACK_BLOCKS (N_NODES * NWORD / 4)          // 65536
#define XCVT_BLOCKS (N_NODES * F_IN / 8 / 256)     // 1024
#define WCVT_BLOCKS (NHEAD * F_OUT * F_IN / 8 / 256) // 128

#if defined(__has_builtin)
#if __has_builtin(__builtin_amdgcn_fdot2)
#define FDOT2(a, b, c) __builtin_amdgcn_fdot2((a), (b), (c), false)
#endif
#endif
#ifndef FDOT2
#define FDOT2(a, b, c) ((c) + (float)(a)[0] * (float)(b)[0] + (float)(a)[1] * (float)(b)[1])
#endif

__device__ inline unsigned short f2bf(float f) {
  unsigned u = __builtin_bit_cast(unsigned, f);
  unsigned r = (u + 0x7FFFu + ((u >> 16) & 1u)) >> 16;
  return (unsigned short)r;
}
__device__ inline float bf2f(unsigned short h) {
  unsigned u = ((unsigned)h) << 16;
  return __builtin_bit_cast(float, u);
}

// ------- pack adjacency bits + x->bf16 + W->Wt[h][o][k] bf16 (one kernel) --
__global__ __launch_bounds__(256) void pack_prep_kernel(
    const int* __restrict__ adj, unsigned long long* __restrict__ bits,
    const float* __restrict__ x, unsigned short* __restrict__ xbf,
    const float* __restrict__ W, unsigned short* __restrict__ Wt) {
  const int b = blockIdx.x;
  const int tid = threadIdx.x;
  if (b < PACK_BLOCKS) {
    int wid = b * 4 + (tid >> 6);
    int l = tid & 63;
    unsigned long long m = __ballot(adj[(size_t)wid * 64 + l] != 0);
    if (l == 0) bits[wid] = m;
  } else if (b < PACK_BLOCKS + XCVT_BLOCKS) {
    int idx = (b - PACK_BLOCKS) * 256 + tid;
    const float* src = x + (size_t)idx * 8;
    float4 v0 = *(const float4*)src;
    float4 v1 = *(const float4*)(src + 4);
    short8 sv;
    sv[0]=f2bf(v0.x); sv[1]=f2bf(v0.y); sv[2]=f2bf(v0.z); sv[3]=f2bf(v0.w);
    sv[4]=f2bf(v1.x); sv[5]=f2bf(v1.y); sv[6]=f2bf(v1.z); sv[7]=f2bf(v1.w);
    *(short8*)&xbf[(size_t)idx * 8] = sv;
  } else {
    int t2 = (b - PACK_BLOCKS - XCVT_BLOCKS) * 256 + tid;   // [0, 32768)
    int h   = t2 >> 12;
    int rem = t2 & 4095;
    int o   = rem >> 6;
    int k8  = rem & 63;
    const float* src = W + ((size_t)(h * F_IN) + k8 * 8) * F_OUT + o;
    short8 sv;
    #pragma unroll
    for (int j = 0; j < 8; ++j) sv[j] = (short)f2bf(src[(size_t)j * F_OUT]);
    *(short8*)&Wt[((size_t)(h * F_OUT) + o) * F_IN + k8 * 8] = sv;
  }
}

// ---------------- GEMM1: DMA-staged tiles (zero staging VALU) --------------
__global__ __launch_bounds__(256) void gemm1_kernel(
    const unsigned short* __restrict__ xbf, const unsigned short* __restrict__ Wt,
    const float* __restrict__ a1, const float* __restrict__ a2,
    unsigned short* __restrict__ WhbT, float* __restrict__ rho1,
    unsigned short* __restrict__ E2f16, unsigned short* __restrict__ E2sf16) {
  __shared__ __align__(16) short As[4 * 512];   // [wave][l*8 shorts]
  __shared__ __align__(16) short Bs[4 * 512];
  __shared__ short Ts[64 * 72];                 // transposed f16 out tile
  const int bx = blockIdx.x;
  const int h  = blockIdx.y;
  const int t  = threadIdx.x;
  const int w  = t >> 6, l = t & 63;
  const int lr = l & 15, ls = l >> 4;
  const unsigned short* asrc = xbf + (size_t)(bx * 64 + w * 16 + lr) * F_IN + ls * 8;
  const unsigned short* bsrc = Wt + (size_t)(h * F_OUT + w * 16 + lr) * F_IN + ls * 8;
  f32x4 acc[4] = {};
  __builtin_amdgcn_global_load_lds(
      (const __attribute__((address_space(1))) void*)asrc,
      (__attribute__((address_space(3))) void*)&As[w * 512], 16, 0, 0);
  __builtin_amdgcn_global_load_lds(
      (const __attribute__((address_space(1))) void*)bsrc,
      (__attribute__((address_space(3))) void*)&Bs[w * 512], 16, 0, 0);
  for (int it = 0; it < F_IN / 32; ++it) {
    asm volatile("s_waitcnt vmcnt(0)" ::: "memory");
    __syncthreads();
    BF8 a, b0, b1, b2, b3;
    a.s  = *(short8*)&As[w * 512 + l * 8];
    b0.s = *(short8*)&Bs[0 * 512 + l * 8];
    b1.s = *(short8*)&Bs[1 * 512 + l * 8];
    b2.s = *(short8*)&Bs[2 * 512 + l * 8];
    b3.s = *(short8*)&Bs[3 * 512 + l * 8];
    asm volatile("s_waitcnt lgkmcnt(0)" ::: "memory");
    __syncthreads();
    if (it + 1 < F_IN / 32) {
      __builtin_amdgcn_global_load_lds(
          (const __attribute__((address_space(1))) void*)(asrc + (it + 1) * 32),
          (__attribute__((address_space(3))) void*)&As[w * 512], 16, 0, 0);
      __builtin_amdgcn_global_load_lds(
          (const __attribute__((address_space(1))) void*)(bsrc + (it + 1) * 32),
          (__attribute__((address_space(3))) void*)&Bs[w * 512], 16, 0, 0);
    }
    acc[0] = __builtin_amdgcn_mfma_f32_16x16x32_bf16(a.b, b0.b, acc[0], 0, 0, 0);
    acc[1] = __builtin_amdgcn_mfma_f32_16x16x32_bf16(a.b, b1.b, acc[1], 0, 0, 0);
    acc[2] = __builtin_amdgcn_mfma_f32_16x16x32_bf16(a.b, b2.b, acc[2], 0, 0, 0);
    acc[3] = __builtin_amdgcn_mfma_f32_16x16x32_bf16(a.b, b3.b, acc[3], 0, 0, 0);
  }
  #pragma unroll
  for (int fc = 0; fc < 4; ++fc)
    #pragma unroll
    for (int j = 0; j < 4; ++j) {
      HU hu; hu.f = (_Float16)acc[fc][j];
      Ts[(fc * 16 + lr) * 72 + (w * 16 + ls * 4 + j)] = (short)hu.u;   // C/D: row=(l>>4)*4+j, col=l&15
    }
  __syncthreads();
  {
    int col = t >> 2, seg = t & 3;
    short8 o0 = *(short8*)&Ts[col * 72 + seg * 16];
    short8 o1 = *(short8*)&Ts[col * 72 + seg * 16 + 8];
    unsigned short* dst = WhbT + (size_t)(h * F_OUT + col) * WST + bx * 64 + seg * 16;
    *(short8*)dst = o0;
    *(short8*)(dst + 8) = o1;
  }
  float a1c[4], a2c[4];
  #pragma unroll
  for (int fc = 0; fc < 4; ++fc) {
    a1c[fc] = a1[h * F_OUT + fc * 16 + lr];
    a2c[fc] = a2[h * F_OUT + fc * 16 + lr];
  }
  #pragma unroll
  for (int j = 0; j < 4; ++j) {
    float s1 = 0.f, s2 = 0.f;
    #pragma unroll
    for (int fc = 0; fc < 4; ++fc) { s1 += acc[fc][j] * a1c[fc]; s2 += acc[fc][j] * a2c[fc]; }
    #pragma unroll
    for (int off = 1; off <= 8; off <<= 1) {
      s1 += __shfl_xor(s1, off, 64);
      s2 += __shfl_xor(s2, off, 64);
    }
    if (lr == 0) {
      int row = bx * 64 + w * 16 + ls * 4 + j;
      int idx = h * N_NODES + row;
      rho1[idx] = __expf((GAT_ALPHA - 1.f) * s1);
      HU u1; u1.f = (_Float16)__expf(s2);
      HU u2; u2.f = (_Float16)__expf(GAT_ALPHA * s2);
      E2f16[idx]  = u1.u;
      E2sf16[idx] = u2.u;
    }
  }
}

// ---------------- ATT1: LDS tables + CB=128 tiles (8 iters, 2 blk/CU) ------
// wave = head (blockIdx.z*4 + wave-in-block), wave-private LDS, no
// __syncthreads. DMA op i covers rows 4i..4i+3; lane l -> row 4i+(l>>4),
// source granule (l&15)^((4i+(l>>4))&15); read granule (kf*4+s)^(r&15):
// LDS[g] = src[g^(R&15)] => read returns src[kf*4+s]. 2-way banks (free).
__global__ __launch_bounds__(256, 2) void att1_kernel(
    const unsigned long long* __restrict__ adjbits,
    const float* __restrict__ rho1,
    const unsigned short* __restrict__ E2f16, const unsigned short* __restrict__ E2sf16,
    const unsigned short* __restrict__ WhbT,
    unsigned short* __restrict__ accPh, float* __restrict__ SP) {
  __shared__ __align__(16) short Bt[4][64 * CB];            // 64 KB
  __shared__ __align__(16) unsigned short Et[4][2][QN];     // 16 KB tables
  const int nb = blockIdx.x * RB;
  const int q  = blockIdx.y;
  const int t  = threadIdx.x;
  const int wl = t >> 6;                    // wave in block
  const int h  = blockIdx.z * 4 + wl;       // global head
  const int l  = t & 63;
  const int r  = l & 15, s = l >> 4;

  const float rho0  = rho1[h * N_NODES + nb + r];
  const float rho1v = rho1[h * N_NODES + nb + 16 + r];
  const v2h rh0 = {(_Float16)rho0, (_Float16)rho0};
  const v2h rh1 = {(_Float16)rho1v, (_Float16)rho1v};
  const v2h ones = {(_Float16)1.0f, (_Float16)1.0f};
  const unsigned short* __restrict__ E2h  = E2f16  + h * N_NODES;
  const unsigned short* __restrict__ E2sh = E2sf16 + h * N_NODES;
  const unsigned long long* __restrict__ ab0 = adjbits + (size_t)(nb + r) * NWORD;
  const unsigned long long* __restrict__ ab1 = adjbits + (size_t)(nb + 16 + r) * NWORD;

  const int tb0 = q * QN;

  // DMA for tile at column base tbD: 16 ops, op i rows 4i..4i+3
#define DMAQ1(tbD) do {                                                       \
    _Pragma("unroll")                                                         \
    for (int i = 0; i < 16; ++i) {                                            \
      const int row = 4 * i + (l >> 4);                                       \
      const int gsw = ((l & 15) ^ (row & 15)) * 8;                            \
      __builtin_amdgcn_global_load_lds(                                       \
        (const __attribute__((address_space(1))) void*)                       \
            (WhbT + (size_t)(h * F_OUT + row) * WST + (tbD) + gsw),           \
        (__attribute__((address_space(3))) void*)&Bt[wl][i * 512], 16, 0, 0); \
    }                                                                         \
  } while (0)

  // prologue: B-tile DMA(0), table DMA (4 ops), masks(0), one-time drain
  DMAQ1(tb0);
  #pragma unroll
  for (int i = 0; i < 2; ++i) {
    __builtin_amdgcn_global_load_lds(
        (const __attribute__((address_space(1))) void*)(E2h + tb0 + i * 512 + l * 8),
        (__attribute__((address_space(3))) void*)&Et[wl][0][i * 512], 16, 0, 0);
    __builtin_amdgcn_global_load_lds(
        (const __attribute__((address_space(1))) void*)(E2sh + tb0 + i * 512 + l * 8),
        (__attribute__((address_space(3))) void*)&Et[wl][1][i * 512], 16, 0, 0);
  }
  unsigned long long mk0a = ab0[tb0 >> 6],       mk1a = ab1[tb0 >> 6];
  unsigned long long mk0b = ab0[(tb0 >> 6) + 1], mk1b = ab1[(tb0 >> 6) + 1];
  asm volatile("s_waitcnt vmcnt(0)" ::: "memory");

  float S0 = 0.f, S1 = 0.f;
  f32x4 acc[2][4] = {};
  for (int it = 0; it < NIT; ++it) {
    const int base = it * CB;
    H8 a0[4], a1f[4];
    #pragma unroll
    for (int kf = 0; kf < 4; ++kf) {
      uint4 ew = *(const uint4*)&Et[wl][0][base + kf * 32 + s * 8];
      uint4 sw = *(const uint4*)&Et[wl][1][base + kf * 32 + s * 8];
      const unsigned ewa[4] = {ew.x, ew.y, ew.z, ew.w};
      const unsigned swa[4] = {sw.x, sw.y, sw.z, sw.w};
      const unsigned sh = (kf & 1) * 32 + s * 8;
      const unsigned bm0 = (unsigned)((kf < 2 ? mk0a : mk0b) >> sh) & 0xffu;
      const unsigned bm1 = (unsigned)((kf < 2 ? mk1a : mk1b) >> sh) & 0xffu;
      #pragma unroll
      for (int p = 0; p < 4; ++p) {
        const v2h e2 = __builtin_bit_cast(v2h, ewa[p]);
        const v2h es = __builtin_bit_cast(v2h, swa[p]);
        const unsigned lo0 = ((bm0 >> (2 * p)) & 1u) ? 0x0000FFFFu : 0u;
        const unsigned hi0 = ((bm0 >> (2 * p + 1)) & 1u) ? 0xFFFF0000u : 0u;
        unsigned q0w = __builtin_bit_cast(unsigned, __builtin_elementwise_max(e2, (v2h)(rh0 * es))) & (lo0 | hi0);
        S0 = FDOT2(__builtin_bit_cast(v2h, q0w), ones, S0);
        a0[kf].w[p] = q0w;
        const unsigned lo1 = ((bm1 >> (2 * p)) & 1u) ? 0x0000FFFFu : 0u;
        const unsigned hi1 = ((bm1 >> (2 * p + 1)) & 1u) ? 0xFFFF0000u : 0u;
        unsigned q1w = __builtin_bit_cast(unsigned, __builtin_elementwise_max(e2, (v2h)(rh1 * es))) & (lo1 | hi1);
        S1 = FDOT2(__builtin_bit_cast(v2h, q1w), ones, S1);
        a1f[kf].w[p] = q1w;
      }
    }
    asm volatile("s_waitcnt vmcnt(0)" ::: "memory");   // B-DMA(it) done
    // masks(it+1): issued before DMA(it+1) -> older in queue
    if (it + 1 < NIT) {
      const int wi = (tb0 + base + CB) >> 6;
      mk0a = ab0[wi]; mk1a = ab1[wi];
      mk0b = ab0[wi + 1]; mk1b = ab1[wi + 1];
    }
    H8 b[4][4];
    #pragma unroll
    for (int kf = 0; kf < 4; ++kf)
      #pragma unroll
      for (int fc = 0; fc < 4; ++fc)
        b[kf][fc].s = *(short8*)&Bt[wl][(fc * 16 + r) * CB + (((kf * 4 + s) ^ (r & 15)) * 8)];
    asm volatile("s_waitcnt lgkmcnt(0)" ::: "memory");
    __builtin_amdgcn_sched_barrier(0);
    if (it + 1 < NIT) DMAQ1(tb0 + base + CB);
    __builtin_amdgcn_sched_barrier(0);
    #pragma unroll
    for (int kf = 0; kf < 4; ++kf)
      #pragma unroll
      for (int fc = 0; fc < 4; ++fc) {
        acc[0][fc] = __builtin_amdgcn_mfma_f32_16x16x32_f16(a0[kf].h,  b[kf][fc].h, acc[0][fc], 0, 0, 0);
        acc[1][fc] = __builtin_amdgcn_mfma_f32_16x16x32_f16(a1f[kf].h, b[kf][fc].h, acc[1][fc], 0, 0, 0);
      }
  }
#undef DMAQ1

  S0 += __shfl_xor(S0, 16, 64); S0 += __shfl_xor(S0, 32, 64);
  S1 += __shfl_xor(S1, 16, 64); S1 += __shfl_xor(S1, 32, 64);
  if (s == 0) {
    SP[((size_t)q * NHEAD + h) * N_NODES + nb + r]      = S0;
    SP[((size_t)q * NHEAD + h) * N_NODES + nb + 16 + r] = S1;
  }
  #pragma unroll
  for (int rg = 0; rg < 2; ++rg)
    #pragma unroll
    for (int fc = 0; fc < 4; ++fc)
      #pragma unroll
      for (int j = 0; j < 4; ++j) {
        int n = nb + rg * 16 + s * 4 + j;          // C/D: row=(l>>4)*4+j
        int col = h * F_OUT + fc * 16 + r;         // C/D: col=l&15
        HU hu; hu.f = (_Float16)acc[rg][fc][j];
        accPh[((size_t)q * N_NODES + n) * HID + col] = hu.u;
      }
}

// ---------------- GEMM2 (fused reduce + ELU): accPh f16 -> Wh2T + tables ---
__global__ __launch_bounds__(256) void gemm2_kernel(
    const unsigned short* __restrict__ accPh, const float* __restrict__ SP,
    const float* __restrict__ Wo,
    const float* __restrict__ ao1, const float* __restrict__ ao2,
    unsigned short* __restrict__ Wh2T, float* __restrict__ rho_o,
    float* __restrict__ Eg2, float* __restrict__ Eg2s) {
  int n = blockIdx.x * 4 + (threadIdx.x >> 6);
  int l = threadIdx.x & 63;
  const int h = l >> 3;                    // head of this lane's 8 hid cols
  float Ssum = 0.f;
  #pragma unroll
  for (int q = 0; q < MSPLIT; ++q) Ssum += SP[((size_t)q * NHEAD + h) * N_NODES + n];
  float v[8] = {};
  #pragma unroll
  for (int q = 0; q < MSPLIT; ++q) {
    H8 u; u.s = *(const short8*)&accPh[((size_t)q * N_NODES + n) * HID + l * 8];
    #pragma unroll
    for (int j = 0; j < 8; ++j) v[j] += (float)u.h[j];
  }
  float rs = 1.0f / Ssum;
  float acc[NCLS] = {};
  #pragma unroll
  for (int j = 0; j < 8; ++j) {
    float e = v[j] * rs;
    e = e > 0.f ? e : (__expf(e) - 1.0f);
    float hv = bf2f(f2bf(e));              // keep bf16 hcat rounding
    const float* wrow = Wo + (l * 8 + j) * NCLS;
    #pragma unroll
    for (int c = 0; c < NCLS; ++c) acc[c] += hv * wrow[c];
  }
  #pragma unroll
  for (int c = 0; c < NCLS; ++c)
    #pragma unroll
    for (int off = 32; off > 0; off >>= 1) acc[c] += __shfl_xor(acc[c], off, 64);
  if (l == 0) {
    float s1 = 0.f, s2 = 0.f;
    #pragma unroll
    for (int c = 0; c < NCLS; ++c) {
      s1 += acc[c] * ao1[c];
      s2 += acc[c] * ao2[c];
    }
    #pragma unroll
    for (int c = 0; c < 16; ++c)
      Wh2T[(size_t)c * N_NODES + n] = (c < NCLS) ? f2bf(acc[c]) : (unsigned short)0;
    rho_o[n] = __expf((GAT_ALPHA - 1.f) * s1);
    Eg2[n]   = __expf(s2);
    Eg2s[n]  = __expf(GAT_ALPHA * s2);
  }
}

// ---------------- ATT2: MFMA PV (P @ Wh2T), in-block combine + log_softmax -
__global__ __launch_bounds__(512) void att2_kernel(
    const unsigned long long* __restrict__ adjbits,
    const float* __restrict__ rho_o,
    const float* __restrict__ Eg2, const float* __restrict__ Eg2s,
    const unsigned short* __restrict__ Wh2T, float* __restrict__ out) {
  __shared__ float Lacc[MS2][RB2][16];
  __shared__ float LS[MS2][RB2];
  const int nb = blockIdx.x * RB2;
  const int t  = threadIdx.x;
  const int w  = t >> 6;               // wave = m-split
  const int l  = t & 63;
  const int r  = l & 15, s = l >> 4;
  const int row = nb + r;
  const float ro = rho_o[row];
  const unsigned long long* __restrict__ ab = adjbits + (size_t)row * NWORD;
  const int tb0 = w * (N_NODES / MS2);

  float S = 0.f;
  f32x4 acc = {};
  for (int it = 0; it < MT2; ++it) {
    const int tb = tb0 + it * 64;
    const unsigned long long mk = ab[tb >> 6];
    BF8 a0[2], b0[2];
    #pragma unroll
    for (int kf = 0; kf < 2; ++kf) {
      const int cb = tb + kf * 32 + s * 8;
      b0[kf].s = *(const short8*)(Wh2T + (size_t)r * N_NODES + cb);
      float4 ea = *(const float4*)(Eg2 + cb);
      float4 eb = *(const float4*)(Eg2 + cb + 4);
      float4 sa = *(const float4*)(Eg2s + cb);
      float4 sb = *(const float4*)(Eg2s + cb + 4);
      float ev[8] = {ea.x, ea.y, ea.z, ea.w, eb.x, eb.y, eb.z, eb.w};
      float sv[8] = {sa.x, sa.y, sa.z, sa.w, sb.x, sb.y, sb.z, sb.w};
      const unsigned bm = (unsigned)(mk >> (kf * 32 + s * 8)) & 0xffu;
      #pragma unroll
      for (int j = 0; j < 8; ++j) {
        float qv = fmaxf(ev[j], ro * sv[j]);
        qv = ((bm >> j) & 1u) ? qv : 0.f;
        S += qv;
        a0[kf].b[j] = (__bf16)qv;
      }
    }
    #pragma unroll
    for (int kf = 0; kf < 2; ++kf)
      acc = __builtin_amdgcn_mfma_f32_16x16x32_bf16(a0[kf].b, b0[kf].b, acc, 0, 0, 0);
  }
  S += __shfl_xor(S, 16, 64);
  S += __shfl_xor(S, 32, 64);
  if (s == 0) LS[w][r] = S;
  #pragma unroll
  for (int j = 0; j < 4; ++j) Lacc[w][s * 4 + j][r] = acc[j];   // D row=s*4+j, col=r
  __syncthreads();
  if (t < 256) {
    const int rr = t >> 4, cc = t & 15;
    float Ssum = 0.f, vsum = 0.f;
    #pragma unroll
    for (int q = 0; q < MS2; ++q) { Ssum += LS[q][rr]; vsum += Lacc[q][rr][cc]; }
    float lo = vsum / Ssum;
    float lom = (cc < NCLS) ? lo : -1e30f;
    float mx = lom;
    #pragma unroll
    for (int off = 1; off <= 8; off <<= 1) mx = fmaxf(mx, __shfl_xor(mx, off, 64));
    float ex = (cc < NCLS) ? __expf(lo - mx) : 0.f;
    float se = ex;
    #pragma unroll
    for (int off = 1; off <= 8; off <<= 1) se += __shfl_xor(se, off, 64);
    float lse = mx + __logf(se);
    if (cc < NCLS) out[(size_t)(nb + rr) * NCLS + cc] = lo - lse;
  }
}

extern "C" void kernel_launch(void* const* d_in, const int* in_sizes, int n_in,
                              void* d_out, int out_size, void* d_ws, size_t ws_size,
                              hipStream_t stream) {
  (void)in_sizes; (void)n_in; (void)out_size; (void)ws_size;
  const float* x   = (const float*)d_in[0];
  const int*   adj = (const int*)d_in[1];
  const float* W   = (const float*)d_in[2];
  const float* a1  = (const float*)d_in[3];
  const float* a2  = (const float*)d_in[4];
  const float* Wo  = (const float*)d_in[5];
  const float* ao1 = (const float*)d_in[6];
  const float* ao2 = (const float*)d_in[7];
  float* out = (float*)d_out;

  char* ws = (char*)d_ws;
  unsigned long long* adjbits = (unsigned long long*)ws; ws += (size_t)N_NODES * NWORD * 8;
  unsigned short* WhbT= (unsigned short*)ws; ws += (size_t)HID * WST * 2;
  unsigned short* accPh = (unsigned short*)ws; ws += (size_t)MSPLIT * N_NODES * HID * 2;
  float* SP           = (float*)ws;          ws += (size_t)MSPLIT * NHEAD * N_NODES * 4;
  float* rho1         = (float*)ws;          ws += (size_t)NHEAD * N_NODES * 4;
  unsigned short* E2f16  = (unsigned short*)ws; ws += (size_t)NHEAD * N_NODES * 2;
  unsigned short* E2sf16 = (unsigned short*)ws; ws += (size_t)NHEAD * N_NODES * 2;
  unsigned short* Wh2T= (unsigned short*)ws; ws += (size_t)16 * N_NODES * 2;
  float* rho_o        = (float*)ws;          ws += (size_t)N_NODES * 4;
  float* Eg2          = (float*)ws;          ws += (size_t)N_NODES * 4;
  float* Eg2s         = (float*)ws;          ws += (size_t)N_NODES * 4;
  unsigned short* xbf = (unsigned short*)ws; ws += (size_t)N_NODES * F_IN * 2;
  unsigned short* Wt  = (unsigned short*)ws; ws += (size_t)NHEAD * F_OUT * F_IN * 2;

  pack_prep_kernel<<<PACK_BLOCKS + XCVT_BLOCKS + WCVT_BLOCKS, 256, 0, stream>>>(
      adj, adjbits, x, xbf, W, Wt);
  gemm1_kernel<<<dim3(64, 8), 256, 0, stream>>>(xbf, Wt, a1, a2, WhbT, rho1, E2f16, E2sf16);
  att1_kernel<<<dim3(N_NODES / RB, MSPLIT, 2), 256, 0, stream>>>(adjbits, rho1, E2f16, E2sf16, WhbT, accPh, SP);
  gemm2_kernel<<<N_NODES / 4, 256, 0, stream>>>(accPh, SP, Wo, ao1, ao2, Wh2T, rho_o, Eg2, Eg2s);
  att2_kernel<<<N_NODES / RB2, 512, 0, stream>>>(adjbits, rho_o, Eg2, Eg2s, Wh2T, out);
}